// Round 3
// baseline (2201.855 us; speedup 1.0000x reference)
//
#include <hip/hip_runtime.h>
#include <cstdint>
#include <cstddef>

#define IN_DIM 512
#define HID 512
#define OUT_DIM 256
#define BN_EPS 1e-5f

typedef unsigned short u16;
typedef short s16x8 __attribute__((ext_vector_type(8)));
typedef float f32x4 __attribute__((ext_vector_type(4)));

__device__ __forceinline__ float gelu_f(float x) {
    return 0.5f * x * (1.0f + erff(x * 0.70710678118654752f));
}
__device__ __forceinline__ float bflo(uint32_t p) {
    uint32_t t = p << 16; float f; __builtin_memcpy(&f, &t, 4); return f;
}
__device__ __forceinline__ float bfhi(uint32_t p) {
    uint32_t t = p & 0xffff0000u; float f; __builtin_memcpy(&f, &t, 4); return f;
}
__device__ __forceinline__ float bfu(u16 u) {
    uint32_t t = (uint32_t)u << 16; float f; __builtin_memcpy(&f, &t, 4); return f;
}
__device__ __forceinline__ u16 f2bf(float f) {   // round-to-nearest-even
    uint32_t x; __builtin_memcpy(&x, &f, 4);
    uint32_t r = x + 0x7fffu + ((x >> 16) & 1u);
    return (u16)(r >> 16);
}
__device__ __forceinline__ void gld_lds16(void* lds, const void* gp) {
    __builtin_amdgcn_global_load_lds(
        (const __attribute__((address_space(1))) void*)gp,
        (__attribute__((address_space(3))) void*)lds, 16, 0, 0);
}

// ---------------- utility ----------------
__global__ void zero_kernel(int* __restrict__ p, int n) {
    int i = blockIdx.x * 256 + threadIdx.x;
    if (i < n) p[i] = 0;
}

// ---------------- CSR build ----------------
__global__ void count_edges(const int* __restrict__ row, int ne, int* __restrict__ counts) {
    int e = blockIdx.x * 256 + threadIdx.x;
    if (e < ne) atomicAdd(&counts[row[e]], 1);
}

template<int BS>
__global__ void scan_block(const int* __restrict__ in, int n,
                           int* __restrict__ out, int* __restrict__ bsums) {
    __shared__ int tmp[BS];
    int t = threadIdx.x;
    int gid = blockIdx.x * BS + t;
    int v = (gid < n) ? in[gid] : 0;
    tmp[t] = v;
    __syncthreads();
    for (int off = 1; off < BS; off <<= 1) {
        int add = (t >= off) ? tmp[t - off] : 0;
        __syncthreads();
        tmp[t] += add;
        __syncthreads();
    }
    if (gid < n) out[gid] = tmp[t] - v;   // exclusive
    if (t == BS - 1 && bsums) bsums[blockIdx.x] = tmp[t];
}

__global__ void scan_add(int* __restrict__ row_start, int* __restrict__ cur_off,
                         const int* __restrict__ bsums, int n) {
    int gid = blockIdx.x * 256 + threadIdx.x;
    if (gid < n) {
        int v = row_start[gid] + bsums[blockIdx.x];
        row_start[gid] = v;
        cur_off[gid] = v;
    }
}

__global__ void scatter_edges(const int* __restrict__ row, const int* __restrict__ col,
                              const float* __restrict__ val, int ne,
                              int* __restrict__ cur_off, int2* __restrict__ epk) {
    int e = blockIdx.x * 256 + threadIdx.x;
    if (e < ne) {
        int r = row[e];
        int p = atomicAdd(&cur_off[r], 1);
        epk[p] = make_int2(col[e], __float_as_int(val[e]));
    }
}

// ---------------- casts ----------------
__global__ __launch_bounds__(256) void cast_to_bf16(const float* __restrict__ in,
                                                    u16* __restrict__ out, size_t n) {
    size_t base = ((size_t)blockIdx.x * 256 + threadIdx.x) * 8;
    if (base >= n) return;
    float4 a = *(const float4*)(in + base);
    float4 b = *(const float4*)(in + base + 4);
    u16 o[8] = {f2bf(a.x), f2bf(a.y), f2bf(a.z), f2bf(a.w),
                f2bf(b.x), f2bf(b.y), f2bf(b.z), f2bf(b.w)};
    uint4 pk; __builtin_memcpy(&pk, o, 16);
    *(uint4*)(out + base) = pk;
}

// in[K,N] fp32 -> out[N,K] bf16
__global__ __launch_bounds__(256) void transpose_cast(const float* __restrict__ in,
                                                      u16* __restrict__ out, int K, int N) {
    __shared__ float t[32][33];
    int tx = threadIdx.x & 31, ty = threadIdx.x >> 5;
    int k0 = blockIdx.x * 32, n0 = blockIdx.y * 32;
#pragma unroll
    for (int i = ty; i < 32; i += 8) t[i][tx] = in[(size_t)(k0 + i) * N + n0 + tx];
    __syncthreads();
#pragma unroll
    for (int i = ty; i < 32; i += 8) out[(size_t)(n0 + i) * K + k0 + tx] = f2bf(t[tx][i]);
}

// ---------------- BN coefficient fold ----------------
__global__ void bn_coeffs(const float* __restrict__ ssum, const float* __restrict__ ssq,
                          const float* __restrict__ gamma, const float* __restrict__ beta,
                          float* __restrict__ s, float* __restrict__ t, int F, float inv_n) {
    int f = blockIdx.x * 256 + threadIdx.x;
    if (f < F) {
        float m = ssum[f] * inv_n;
        float var = ssq[f] * inv_n - m * m;
        float sc = rsqrtf(var + BN_EPS) * gamma[f];
        s[f] = sc;
        t[f] = beta[f] - m * sc;
    }
}

// W[n,k] *= s[k]  (bf16 in place), K power of 2
__global__ __launch_bounds__(256) void scale_cols_bf16(u16* __restrict__ W,
                                                       const float* __restrict__ s,
                                                       int total, int K) {
    int idx = blockIdx.x * 256 + threadIdx.x;
    if (idx < total) {
        int k = idx & (K - 1);
        W[idx] = f2bf(bfu(W[idx]) * s[k]);
    }
}

// biasp[n] = ba[n] + sum_k t[k] * Wa1[k*Nout + n]   (Wa1 fp32 [K, Nout])
__global__ void fold_bias(const float* __restrict__ Wa1, const float* __restrict__ ba,
                          const float* __restrict__ t, float* __restrict__ biasp,
                          int K, int Nout) {
    int n = threadIdx.x;
    if (n >= Nout) return;
    float acc = ba[n];
    for (int k = 0; k < K; ++k) acc = fmaf(t[k], Wa1[(size_t)k * Nout + n], acc);
    biasp[n] = acc;
}

// ---------------- bf16 MFMA GEMM: C[M,N] = A[M,K] @ Bt[N,K]^T ----------------
// EPI: 0 = none, 1 = relu(acc+bias), 2 = (extra*gs+gt) * sigmoid(acc+bias). C bf16.
template<int EPI>
__global__ __launch_bounds__(256) void gemm_bt(
    const u16* __restrict__ A, const u16* __restrict__ Bt,
    u16* __restrict__ C, const float* __restrict__ bias,
    const u16* __restrict__ extra, const float* __restrict__ gs,
    const float* __restrict__ gt, int M, int N, int K)
{
    __shared__ u16 Alds[128 * 32];
    __shared__ u16 Blds[128 * 32];
    const int tid = threadIdx.x;
    const int wid = tid >> 6, lane = tid & 63;
    const int wm = wid >> 1, wn = wid & 1;
    const int row0 = blockIdx.x * 128, col0 = blockIdx.y * 128;
    const int srow = lane >> 2;
    const int scol = (lane & 3) * 8;
    const int fr = lane & 15;
    const int fk = (lane >> 4) * 8;

    f32x4 acc[4][4];
#pragma unroll
    for (int i = 0; i < 4; ++i)
#pragma unroll
        for (int j = 0; j < 4; ++j) acc[i][j] = f32x4{0.f, 0.f, 0.f, 0.f};

    for (int k0 = 0; k0 < K; k0 += 32) {
#pragma unroll
        for (int c = 0; c < 2; ++c) {
            int tr = wid * 32 + c * 16 + srow;
            int ar = row0 + tr; if (ar >= M) ar = M - 1;
            gld_lds16(&Alds[(wid * 32 + c * 16) * 32], A + (size_t)ar * K + k0 + scol);
            gld_lds16(&Blds[(wid * 32 + c * 16) * 32], Bt + (size_t)(col0 + tr) * K + k0 + scol);
        }
        __syncthreads();
        s16x8 af[4], bfv[4];
#pragma unroll
        for (int m = 0; m < 4; ++m)
            af[m] = *(const s16x8*)&Alds[(wm * 64 + m * 16 + fr) * 32 + fk];
#pragma unroll
        for (int n = 0; n < 4; ++n)
            bfv[n] = *(const s16x8*)&Blds[(wn * 64 + n * 16 + fr) * 32 + fk];
#pragma unroll
        for (int m = 0; m < 4; ++m)
#pragma unroll
            for (int n = 0; n < 4; ++n)
                acc[m][n] = __builtin_amdgcn_mfma_f32_16x16x32_bf16(af[m], bfv[n], acc[m][n], 0, 0, 0);
        __syncthreads();
    }

#pragma unroll
    for (int n = 0; n < 4; ++n) {
        const int c = col0 + wn * 64 + n * 16 + fr;
        float bv = 0.f, sv = 0.f, tv = 0.f;
        if (EPI != 0) bv = bias[c];
        if (EPI == 2) { sv = gs[c]; tv = gt[c]; }
#pragma unroll
        for (int m = 0; m < 4; ++m) {
            const int rbase = row0 + wm * 64 + m * 16 + (lane >> 4) * 4;
#pragma unroll
            for (int q = 0; q < 4; ++q) {
                int rr = rbase + q;
                if (rr < M) {
                    float v = acc[m][n][q];
                    if (EPI == 1) v = fmaxf(v + bv, 0.f);
                    else if (EPI == 2) {
                        float ev = bfu(extra[(size_t)rr * N + c]) * sv + tv;
                        v = ev / (1.f + expf(-(v + bv)));
                    }
                    C[(size_t)rr * N + c] = f2bf(v);
                }
            }
        }
    }
}

// ---------------- SpMM: one wave per row, 16B/lane gathers ----------------
// F=512: 4 words (8 feats)/lane via uint4; F=256: 2 words (4 feats)/lane via uint2.
template<int F, bool OUTBF>
__global__ __launch_bounds__(256) void spmm_wave(
    const u16* __restrict__ sup, const int2* __restrict__ epk,
    const int* __restrict__ row_start, const int* __restrict__ counts,
    const float* __restrict__ bias, float* __restrict__ outf,
    u16* __restrict__ outb, int n)
{
    constexpr int WPR = F / 128;          // uint32 words per lane
    constexpr int FPL = 2 * WPR;          // feats per lane
    const int lane = threadIdx.x & 63;
    const int row = blockIdx.x * 4 + (threadIdx.x >> 6);
    if (row >= n) return;
    const int start = row_start[row];
    const int nnz = counts[row];
    const uint32_t* supu = (const uint32_t*)sup;
    const size_t lbase = (size_t)lane * WPR;

    float acc[FPL];
#pragma unroll
    for (int k = 0; k < FPL; ++k) acc[k] = 0.f;

    int j = 0;
    for (; j + 4 <= nnz; j += 4) {
        int2 e[4];
#pragma unroll
        for (int u = 0; u < 4; ++u) e[u] = epk[start + j + u];
#pragma unroll
        for (int u = 0; u < 4; ++u) {
            const uint32_t* p = &supu[(size_t)e[u].x * (F / 2) + lbase];
            float v = __int_as_float(e[u].y);
            if (WPR == 4) {
                uint4 q = *(const uint4*)p;
                acc[0] = fmaf(v, bflo(q.x), acc[0]); acc[1] = fmaf(v, bfhi(q.x), acc[1]);
                acc[2] = fmaf(v, bflo(q.y), acc[2]); acc[3] = fmaf(v, bfhi(q.y), acc[3]);
                acc[4] = fmaf(v, bflo(q.z), acc[4]); acc[5] = fmaf(v, bfhi(q.z), acc[5]);
                acc[6] = fmaf(v, bflo(q.w), acc[6]); acc[7] = fmaf(v, bfhi(q.w), acc[7]);
            } else {
                uint2 q = *(const uint2*)p;
                acc[0] = fmaf(v, bflo(q.x), acc[0]); acc[1] = fmaf(v, bfhi(q.x), acc[1]);
                acc[2] = fmaf(v, bflo(q.y), acc[2]); acc[3] = fmaf(v, bfhi(q.y), acc[3]);
            }
        }
    }
    for (; j < nnz; ++j) {
        int2 e = epk[start + j];
        const uint32_t* p = &supu[(size_t)e.x * (F / 2) + lbase];
        float v = __int_as_float(e.y);
        if (WPR == 4) {
            uint4 q = *(const uint4*)p;
            acc[0] = fmaf(v, bflo(q.x), acc[0]); acc[1] = fmaf(v, bfhi(q.x), acc[1]);
            acc[2] = fmaf(v, bflo(q.y), acc[2]); acc[3] = fmaf(v, bfhi(q.y), acc[3]);
            acc[4] = fmaf(v, bflo(q.z), acc[4]); acc[5] = fmaf(v, bfhi(q.z), acc[5]);
            acc[6] = fmaf(v, bflo(q.w), acc[6]); acc[7] = fmaf(v, bfhi(q.w), acc[7]);
        } else {
            uint2 q = *(const uint2*)p;
            acc[0] = fmaf(v, bflo(q.x), acc[0]); acc[1] = fmaf(v, bfhi(q.x), acc[1]);
            acc[2] = fmaf(v, bflo(q.y), acc[2]); acc[3] = fmaf(v, bfhi(q.y), acc[3]);
        }
    }

    const int f0 = lane * FPL;
    float o[FPL];
#pragma unroll
    for (int k = 0; k < FPL; ++k) o[k] = gelu_f(acc[k] + bias[f0 + k]);

    if (OUTBF) {
        u16 pk[FPL];
#pragma unroll
        for (int k = 0; k < FPL; ++k) pk[k] = f2bf(o[k]);
        if (WPR == 4) {
            uint4 w; __builtin_memcpy(&w, pk, 16);
            *(uint4*)&outb[(size_t)row * F + f0] = w;
        } else {
            uint2 w; __builtin_memcpy(&w, pk, 8);
            *(uint2*)&outb[(size_t)row * F + f0] = w;
        }
    } else {
        if (WPR == 2) {
            float4 w = make_float4(o[0], o[1], o[2], o[3]);
            *(float4*)&outf[(size_t)row * F + f0] = w;
        } else {
#pragma unroll
            for (int k = 0; k < FPL; k += 4) {
                float4 w = make_float4(o[k], o[k + 1], o[k + 2], o[k + 3]);
                *(float4*)&outf[(size_t)row * F + f0 + k] = w;
            }
        }
    }
}

// ---------------- BatchNorm reduce (bf16) ----------------
template<int F>
__global__ __launch_bounds__(256) void bn_reduce_bf16(const u16* __restrict__ x, int n,
                                                      float* __restrict__ ssum,
                                                      float* __restrict__ ssq) {
    const int tid = threadIdx.x;
    int r0 = blockIdx.x * 256, rend = min(r0 + 256, n);
    const uint32_t* xu = (const uint32_t*)x;
    float s0 = 0, s1 = 0, q0 = 0, q1 = 0;
    for (int r = r0; r < rend; ++r) {
        uint32_t p = xu[(size_t)r * (F / 2) + tid];
        float v0 = bflo(p), v1 = bfhi(p);
        s0 += v0; q0 += v0 * v0;
        s1 += v1; q1 += v1 * v1;
    }
    atomicAdd(&ssum[2 * tid], s0);     atomicAdd(&ssum[2 * tid + 1], s1);
    atomicAdd(&ssq[2 * tid], q0);      atomicAdd(&ssq[2 * tid + 1], q1);
}

// ---------------- BatchNorm (fp32, final layer) ----------------
template<int F>
__global__ __launch_bounds__(256) void bn_reduce(const float* __restrict__ x, int n,
                                                 float* __restrict__ ssum, float* __restrict__ ssq) {
    constexpr int NV = F / 256;
    int tid = threadIdx.x;
    int r0 = blockIdx.x * 256, rend = min(r0 + 256, n);
    float s[NV] = {}, q[NV] = {};
    for (int r = r0; r < rend; ++r) {
#pragma unroll
        for (int k = 0; k < NV; ++k) {
            float v = x[(size_t)r * F + tid + k * 256];
            s[k] += v; q[k] += v * v;
        }
    }
#pragma unroll
    for (int k = 0; k < NV; ++k) {
        atomicAdd(&ssum[tid + k * 256], s[k]);
        atomicAdd(&ssq[tid + k * 256], q[k]);
    }
}

template<int F>
__global__ __launch_bounds__(256) void bn_apply(float* __restrict__ x, int n,
                                                const float* __restrict__ ssum,
                                                const float* __restrict__ ssq,
                                                const float* __restrict__ gamma,
                                                const float* __restrict__ beta) {
    float inv_n = 1.0f / (float)n;
    size_t total4 = (size_t)n * F / 4;
    for (size_t i = (size_t)blockIdx.x * 256 + threadIdx.x; i < total4;
         i += (size_t)gridDim.x * 256) {
        float4 v = ((const float4*)x)[i];
        int f0 = (int)((i * 4) & (size_t)(F - 1));
        float in[4] = {v.x, v.y, v.z, v.w};
#pragma unroll
        for (int k = 0; k < 4; ++k) {
            int f = f0 + k;
            float mean = ssum[f] * inv_n;
            float var = ssq[f] * inv_n - mean * mean;
            float sc = rsqrtf(var + BN_EPS) * gamma[f];
            in[k] = (in[k] - mean) * sc + beta[f];
        }
        v.x = in[0]; v.y = in[1]; v.z = in[2]; v.w = in[3];
        ((float4*)x)[i] = v;
    }
}

// ---------------- launch ----------------
extern "C" void kernel_launch(void* const* d_in, const int* in_sizes, int n_in,
                              void* d_out, int out_size, void* d_ws, size_t ws_size,
                              hipStream_t stream) {
    const float* x       = (const float*)d_in[0];
    const int*   adj_row = (const int*)d_in[1];
    const int*   adj_col = (const int*)d_in[2];
    const float* adj_val = (const float*)d_in[3];
    const float* W1      = (const float*)d_in[4];
    const float* b1      = (const float*)d_in[5];
    const float* gamma1  = (const float*)d_in[6];
    const float* beta1   = (const float*)d_in[7];
    const float* Wa1     = (const float*)d_in[8];
    const float* ba1     = (const float*)d_in[9];
    const float* Wa2     = (const float*)d_in[10];
    const float* ba2     = (const float*)d_in[11];
    const float* W2      = (const float*)d_in[12];
    const float* b2      = (const float*)d_in[13];
    const float* gamma2  = (const float*)d_in[14];
    const float* beta2   = (const float*)d_in[15];

    const int N = in_sizes[0] / IN_DIM;   // 100000
    const int E = in_sizes[1];            // 3200000

    char* ws = (char*)d_ws;
    size_t off = 0;
    auto alloc = [&](size_t bytes) -> void* {
        void* p = ws + off;
        off = (off + bytes + 255) & ~(size_t)255;
        return p;
    };
    u16*  x16    = (u16*)alloc((size_t)N * IN_DIM * 2);   // x bf16; reused as gated16
    u16*  sup16  = (u16*)alloc((size_t)N * HID * 2);      // support1, then support2
    u16*  x1_16  = (u16*)alloc((size_t)N * HID * 2);      // x1 raw (pre-BN) bf16
    u16*  h16    = (u16*)alloc((size_t)N * (HID / 4) * 2);
    int2* epk    = (int2*)alloc((size_t)E * 8);
    int*  counts = (int*)alloc((size_t)N * 4);
    int*  row_st = (int*)alloc((size_t)N * 4);
    int*  cur_of = (int*)alloc((size_t)N * 4);
    int*  bsums  = (int*)alloc(4096);
    float* stats = (float*)alloc(1536 * 4);
    float* s1    = (float*)alloc(512 * 4);
    float* t1    = (float*)alloc(512 * 4);
    float* bias1p= (float*)alloc(128 * 4);
    u16*  W1t    = (u16*)alloc(512 * 512 * 2);
    u16*  Wa1t   = (u16*)alloc(128 * 512 * 2);
    u16*  Wa2t   = (u16*)alloc(512 * 128 * 2);
    u16*  W2t    = (u16*)alloc(256 * 512 * 2);
    float* ssum1 = stats, *ssq1 = stats + 512, *ssum2 = stats + 1024, *ssq2 = stats + 1280;
    u16*  gated16 = x16;   // reuse after gemm1 consumed x16

    const int nb_n = (N + 255) / 256;   // 391
    const int nb_e = (E + 255) / 256;
    const int gm = (N + 127) / 128;     // 782
    const int sg = (N + 3) / 4;         // 25000 (spmm wave blocks)

    // CSR build + stat zero
    zero_kernel<<<nb_n, 256, 0, stream>>>(counts, N);
    zero_kernel<<<6, 256, 0, stream>>>((int*)stats, 1536);
    count_edges<<<nb_e, 256, 0, stream>>>(adj_row, E, counts);
    scan_block<256><<<nb_n, 256, 0, stream>>>(counts, N, row_st, bsums);
    scan_block<512><<<1, 512, 0, stream>>>(bsums, nb_n, bsums, nullptr);
    scan_add<<<nb_n, 256, 0, stream>>>(row_st, cur_of, bsums, N);
    scatter_edges<<<nb_e, 256, 0, stream>>>(adj_row, adj_col, adj_val, E, cur_of, epk);

    // casts
    cast_to_bf16<<<(int)(((size_t)N * IN_DIM + 2047) / 2048), 256, 0, stream>>>(x, x16, (size_t)N * IN_DIM);
    transpose_cast<<<dim3(16, 16), 256, 0, stream>>>(W1, W1t, IN_DIM, HID);
    transpose_cast<<<dim3(16, 4), 256, 0, stream>>>(Wa1, Wa1t, HID, HID / 4);
    transpose_cast<<<dim3(4, 16), 256, 0, stream>>>(Wa2, Wa2t, HID / 4, HID);
    transpose_cast<<<dim3(16, 8), 256, 0, stream>>>(W2, W2t, HID, OUT_DIM);

    // layer 1 (x1_16 holds RAW gelu output; BN1 is folded forward)
    gemm_bt<0><<<dim3(gm, HID / 128), 256, 0, stream>>>(x16, W1t, sup16, nullptr, nullptr, nullptr, nullptr, N, HID, IN_DIM);
    spmm_wave<HID, true><<<sg, 256, 0, stream>>>(sup16, epk, row_st, counts, b1, nullptr, x1_16, N);
    bn_reduce_bf16<HID><<<nb_n, 256, 0, stream>>>(x1_16, N, ssum1, ssq1);
    bn_coeffs<<<2, 256, 0, stream>>>(ssum1, ssq1, gamma1, beta1, s1, t1, HID, 1.0f / N);
    scale_cols_bf16<<<(128 * 512) / 256, 256, 0, stream>>>(Wa1t, s1, 128 * 512, 512);
    fold_bias<<<1, 128, 0, stream>>>(Wa1, ba1, t1, bias1p, HID, HID / 4);

    // attention gate: relu((x1*s+t) @ Wa1 + ba1) == relu(x1 @ Wa1' + bias1p)
    gemm_bt<1><<<dim3(gm, 1), 256, 0, stream>>>(x1_16, Wa1t, h16, bias1p, nullptr, nullptr, nullptr, N, HID / 4, HID);
    // gated = (x1*s+t) * sigmoid(h @ Wa2 + ba2)
    gemm_bt<2><<<dim3(gm, HID / 128), 256, 0, stream>>>(h16, Wa2t, gated16, ba2, x1_16, s1, t1, N, HID, HID / 4);

    // layer 2
    gemm_bt<0><<<dim3(gm, OUT_DIM / 128), 256, 0, stream>>>(gated16, W2t, sup16, nullptr, nullptr, nullptr, nullptr, N, OUT_DIM, HID);
    spmm_wave<OUT_DIM, false><<<sg, 256, 0, stream>>>(sup16, epk, row_st, counts, b2, (float*)d_out, nullptr, N);
    bn_reduce<OUT_DIM><<<nb_n, 256, 0, stream>>>((float*)d_out, N, ssum2, ssq2);
    bn_apply<OUT_DIM><<<2048, 256, 0, stream>>>((float*)d_out, N, ssum2, ssq2, gamma2, beta2);
}